// Round 9
// baseline (271.235 us; speedup 1.0000x reference)
//
#include <hip/hip_runtime.h>
#include <stdint.h>

// B=128, K_fc=32 -> 4096 rows, F=2048, K_LIST={64,128,256,512}, TAU=1, EPS=1e-20.
// Output = M_hard exactly (straight-through term is numerically zero forward).
//
// R9: wave-per-row select machinery (12-bit packed-u16 radix hist, wave scan,
// gated bin-find, all-pairs on tiny threshold bin; zero real barriers), but
// each wave runs TWO rows with phases cross-interleaved in its instruction
// stream: row-B loads issued during row-A key-build; row-A mask stores
// interleaved with row-B logf key-build (stores drain on VMEM under VALU).
// This bakes read/VALU/write mixing into the code instead of relying on
// wave scheduling (R8 showed the device runs phase-locked bursts).

#define F_DIM  2048
#define KSB    4
#define CAP    512

typedef float f32x4 __attribute__((ext_vector_type(4)));

// Monotonic descending key: kd(a) < kd(b)  <=>  a > b (total order on f32)
__device__ __forceinline__ uint32_t f32_desc_key(float x) {
    uint32_t u = __float_as_uint(x);
    uint32_t ka = (u & 0x80000000u) ? ~u : (u | 0x80000000u);
    return ~ka;
}

__device__ __forceinline__ void zero_hist(uint32_t* hist, int L, uint32_t* selCnt) {
    uint4 z = {0u, 0u, 0u, 0u};
    #pragma unroll
    for (int i = 0; i < 8; ++i) ((uint4*)hist)[64 * i + L] = z;   // 2048 words
    if (L < 16) ((uint4*)hist)[512 + L] = z;                      // pad tail
    if (L < KSB) selCnt[L] = 0;
}

// keys for 4 elements + histogram atomics (12-bit digit, packed u16, padded)
__device__ __forceinline__ void keychunk(const float4 sv, const float4 uv,
                                         uint32_t* d, uint32_t* hist) {
    float ss[4] = {sv.x, sv.y, sv.z, sv.w};
    float uu[4] = {uv.x, uv.y, uv.z, uv.w};
    #pragma unroll
    for (int j = 0; j < 4; ++j) {
        float inner = -logf(uu[j] + 1e-20f);   // byte-identical reference math
        float g     = -logf(inner + 1e-20f);
        uint32_t k  = f32_desc_key(ss[j] + g);
        d[j] = k;
        uint32_t dg = k >> 20;
        uint32_t w  = dg >> 1;
        atomicAdd(&hist[w + (w >> 5)], 1u << ((dg & 1u) << 4));
    }
}

// masks for 4 elements x 4 K-planes, nontemporal stores
__device__ __forceinline__ void epichunk(const uint32_t* d,
                                         const unsigned long long* T,
                                         float* outrow, int off) {
    f32x4 m0, m1, m2, m3;
    #pragma unroll
    for (int j = 0; j < 4; ++j) {
        unsigned long long k = (((unsigned long long)d[j]) << 11) |
                               (unsigned long long)(uint32_t)(off + j);
        m0[j] = (k <= T[0]) ? 1.0f : 0.0f;
        m1[j] = (k <= T[1]) ? 1.0f : 0.0f;
        m2[j] = (k <= T[2]) ? 1.0f : 0.0f;
        m3[j] = (k <= T[3]) ? 1.0f : 0.0f;
    }
    __builtin_nontemporal_store(m0, (f32x4*)(outrow + 0 * F_DIM + off));
    __builtin_nontemporal_store(m1, (f32x4*)(outrow + 1 * F_DIM + off));
    __builtin_nontemporal_store(m2, (f32x4*)(outrow + 2 * F_DIM + off));
    __builtin_nontemporal_store(m3, (f32x4*)(outrow + 3 * F_DIM + off));
}

// full selection for one row; hist must hold the row's histogram.
// Leaves thresholds (wave-uniform, SGPR via readfirstlane) in T[4].
__device__ __forceinline__ void select_row(uint32_t* hist, uint32_t* selScr,
                                           uint32_t* selCnt, uint32_t* selThr,
                                           const uint32_t* d32, int L,
                                           unsigned long long* T) {
    // wave scan: lane L owns logical words 32L..32L+31 (bins 64L..64L+63)
    uint32_t w[32];
    #pragma unroll
    for (int i = 0; i < 32; ++i) w[i] = hist[33 * L + i];  // 2-way aliasing: free
    uint32_t run = 0;
    #pragma unroll
    for (int i = 0; i < 32; ++i) run += (w[i] & 0xFFFFu) + (w[i] >> 16);
    uint32_t v = run;
    #pragma unroll
    for (int d = 1; d < 64; d <<= 1) {
        uint32_t n = __shfl_up(v, (unsigned)d, 64);
        if (L >= d) v += n;
    }
    const uint32_t thrOff = v - run;

    // gated bin-find
    {
        const uint32_t Ks[KSB] = {64u, 128u, 256u, 512u};
        #pragma unroll
        for (int s = 0; s < KSB; ++s) {
            uint32_t r = Ks[s] - 1u;
            if (r >= thrOff && r < thrOff + run) {       // exactly one lane
                uint32_t acc = thrOff;
                #pragma unroll
                for (int i = 0; i < 32; ++i) {
                    uint32_t c0 = w[i] & 0xFFFFu, c1 = w[i] >> 16;
                    if (r >= acc && r < acc + c0) selScr[s] = ((64u*L + 2u*i) << 12) | (r - acc);
                    acc += c0;
                    if (r >= acc && r < acc + c1) selScr[s] = ((64u*L + 2u*i + 1u) << 12) | (r - acc);
                    acc += c1;
                }
            }
        }
    }
    __syncthreads();

    // collect threshold-bin members (hist dead -> reuse as cand[4][CAP])
    uint32_t (*cand)[CAP] = (uint32_t (*)[CAP])hist;
    const uint32_t b0 = selScr[0] >> 12, b1 = selScr[1] >> 12,
                   b2 = selScr[2] >> 12, b3 = selScr[3] >> 12;
    #pragma unroll
    for (int c = 0; c < 8; ++c) {
        #pragma unroll
        for (int j = 0; j < 4; ++j) {
            uint32_t k   = d32[4 * c + j];
            uint32_t dg  = k >> 20;
            uint32_t p31 = ((k & 0xFFFFFu) << 11) | (uint32_t)(256 * c + 4 * L + j);
            if (dg == b0) { uint32_t p = atomicAdd(&selCnt[0], 1u); if (p < CAP) cand[0][p] = p31; }
            if (dg == b1) { uint32_t p = atomicAdd(&selCnt[1], 1u); if (p < CAP) cand[1][p] = p31; }
            if (dg == b2) { uint32_t p = atomicAdd(&selCnt[2], 1u); if (p < CAP) cand[2][p] = p31; }
            if (dg == b3) { uint32_t p = atomicAdd(&selCnt[3], 1u); if (p < CAP) cand[3][p] = p31; }
        }
    }
    __syncthreads();

    // all-pairs rank within each tiny bin
    #pragma unroll
    for (int s = 0; s < KSB; ++s) {
        const uint32_t C = min(selCnt[s], (uint32_t)CAP);
        const uint32_t r = selScr[s] & 0xFFFu;
        for (uint32_t i = L; i < C; i += 64) {
            uint32_t ci = cand[s][i];
            uint32_t cnt = 0;
            for (uint32_t j = 0; j < C; ++j) cnt += (cand[s][j] < ci);  // broadcast
            if (cnt == r) selThr[s] = ci;    // unique keys -> one writer
        }
    }
    __syncthreads();

    // thresholds -> SGPRs (key = (digit<<31) | packed31)
    #pragma unroll
    for (int s = 0; s < KSB; ++s) {
        uint32_t b  = (uint32_t)__builtin_amdgcn_readfirstlane((int)(selScr[s] >> 12));
        uint32_t th = (uint32_t)__builtin_amdgcn_readfirstlane((int)selThr[s]);
        T[s] = (((unsigned long long)b) << 31) | (unsigned long long)th;
    }
    __syncthreads();   // all-pairs/cand reads done before caller re-zeroes hist
}

__global__ __launch_bounds__(64, 4)
void hsb_kernel(const float* __restrict__ scores,
                const float* __restrict__ uin,
                float* __restrict__ out) {
    const int rowA = blockIdx.x * 2;
    const int rowB = rowA + 1;
    const int L    = threadIdx.x;          // lane 0..63 (one wave per block)

    __shared__ uint32_t hist[2112];        // 4096 u16 bins packed + 1 pad/32
    __shared__ uint32_t selScr[KSB];
    __shared__ uint32_t selCnt[KSB];
    __shared__ uint32_t selThr[KSB];

    const float4* sA = (const float4*)(scores + rowA * F_DIM);
    const float4* uA = (const float4*)(uin    + rowA * F_DIM);
    const float4* sB = (const float4*)(scores + rowB * F_DIM);
    const float4* uB = (const float4*)(uin    + rowB * F_DIM);

    // ---- issue row-A loads; zero hist while they fly ----
    float4 lsA[8], luA[8];
    #pragma unroll
    for (int c = 0; c < 8; ++c) { lsA[c] = sA[64 * c + L]; luA[c] = uA[64 * c + L]; }
    zero_hist(hist, L, selCnt);
    __syncthreads();                       // single-wave: folds to waitcnt

    // ---- key-build A, with row-B loads issued as A's staging regs free ----
    uint32_t dA[32];
    float4 lsB[8], luB[8];
    #pragma unroll
    for (int c = 0; c < 8; ++c) {
        keychunk(lsA[c], luA[c], &dA[4 * c], hist);
        lsB[c] = sB[64 * c + L];  luB[c] = uB[64 * c + L];   // prefetch B
    }
    __syncthreads();

    // ---- select A ----
    unsigned long long TA[KSB];
    select_row(hist, selScr, selCnt, selThr, dA, L, TA);

    // ---- re-zero hist for B ----
    zero_hist(hist, L, selCnt);
    __syncthreads();

    // ---- key-build B interleaved with epilogue A (stores drain under VALU) ----
    uint32_t dB[32];
    float* outA = out + (size_t)rowA * (KSB * F_DIM);
    #pragma unroll
    for (int c = 0; c < 8; ++c) {
        keychunk(lsB[c], luB[c], &dB[4 * c], hist);
        epichunk(&dA[4 * c], TA, outA, 256 * c + 4 * L);
    }
    __syncthreads();

    // ---- select B ----
    unsigned long long TB[KSB];
    select_row(hist, selScr, selCnt, selThr, dB, L, TB);

    // ---- epilogue B (exposed tail; block-drift staggers it device-wide) ----
    float* outB = out + (size_t)rowB * (KSB * F_DIM);
    #pragma unroll
    for (int c = 0; c < 8; ++c)
        epichunk(&dB[4 * c], TB, outB, 256 * c + 4 * L);
}

extern "C" void kernel_launch(void* const* d_in, const int* in_sizes, int n_in,
                              void* d_out, int out_size, void* d_ws, size_t ws_size,
                              hipStream_t stream) {
    const float* scores = (const float*)d_in[0];
    const float* u      = (const float*)d_in[1];
    float* out          = (float*)d_out;
    const int rows = in_sizes[0] / F_DIM;  // 4096
    hsb_kernel<<<dim3(rows / 2), dim3(64), 0, stream>>>(scores, u, out);
}